// Round 2
// baseline (543.729 us; speedup 1.0000x reference)
//
#include <hip/hip_runtime.h>
#include <hip/hip_bf16.h>

typedef __bf16 v8bf __attribute__((ext_vector_type(8)));
typedef float  v4f  __attribute__((ext_vector_type(4)));

// ---------------------------------------------------------------------------
// k0: convert W2 (fp32, 512x512 row-major [k][n]) to bf16 in MFMA B-fragment
//     order: w2f[ctg(32)][kt(16)][lane(64)][j(8)], where for
//     mfma_f32_16x16x32_bf16 B-frag: n = ctg*16 + (lane&15),
//     k = kt*32 + (lane>>4)*8 + j. Hot-loop b-frag load becomes a coalesced
//     16B/lane read.
// ---------------------------------------------------------------------------
__global__ __launch_bounds__(256) void k0_w2swizzle(const float* __restrict__ W2,
                                                    __bf16* __restrict__ w2f) {
    int tid = blockIdx.x * 256 + threadIdx.x;   // 0..32767
    int ctg  = tid >> 10;                       // 0..31
    int kt   = (tid >> 6) & 15;                 // 0..15
    int lane = tid & 63;
    int quad = lane >> 4, col = lane & 15;
    int n = ctg * 16 + col;
    int kbase = kt * 32 + quad * 8;
    v8bf v;
#pragma unroll
    for (int j = 0; j < 8; ++j) v[j] = (__bf16)W2[(kbase + j) * 512 + n];
    *(v8bf*)&w2f[(size_t)tid * 8] = v;
}

// ---------------------------------------------------------------------------
// k1: eqc[b][d] = (emotion[b,:] @ W1)[d] + b1[d] + b2[d]   (all fp32)
//     Also zero-inits the logits accumulator (k2 uses atomicAdd).
// ---------------------------------------------------------------------------
__global__ __launch_bounds__(256) void k1_eq(const float* __restrict__ emo,
                                             const float* __restrict__ W1,
                                             const float* __restrict__ b1,
                                             const float* __restrict__ b2,
                                             float* __restrict__ eqc,
                                             float* __restrict__ logits) {
    int b = blockIdx.x, t = threadIdx.x;
    // zero logits: 8 blocks * 256 threads * 32 = 65536
#pragma unroll
    for (int i = 0; i < 32; ++i) logits[(b * 256 + t) * 32 + i] = 0.f;

    __shared__ float emos[512];
    emos[t]       = emo[b * 512 + t];
    emos[t + 256] = emo[b * 512 + t + 256];
    __syncthreads();
#pragma unroll
    for (int rep = 0; rep < 2; ++rep) {
        int d = t + rep * 256;
        float acc = 0.f;
        for (int k = 0; k < 512; ++k) acc += emos[k] * W1[k * 512 + d];
        eqc[b * 512 + d] = acc + b1[d] + b2[d];
    }
}

// ---------------------------------------------------------------------------
// k2: fused  logits[r] = sum_d tanh(eqc[b,d] + (sents@W2)[r,d]) * W3[d]
//     64 rows/block; sents tile converted fp32->bf16 into 64KB LDS with an
//     XOR-16B-chunk swizzle (chunk c of row r stored at c ^ (r&15)) ->
//     conflict-free ds_read_b128 without padding past the 64KB LDS limit.
//     4 waves: (row_half, col_half) 2x2 split; each wave 32 rows x 256 cols,
//     2x2 fragment grid per 32-col tile, mfma_f32_16x16x32_bf16.
//     Layouts (learn_hip m89/m120): A: m=lane&15, k=quad*8+j;
//     B: n=lane&15, k=quad*8+j; C/D: col=lane&15, row=quad*4+reg.
// ---------------------------------------------------------------------------
__global__ __launch_bounds__(256) void k2_logits(const float* __restrict__ sents,
                                                 const __bf16* __restrict__ w2f,
                                                 const float* __restrict__ eqc,
                                                 const float* __restrict__ W3,
                                                 float* __restrict__ logits) {
    __shared__ __bf16 As[64 * 512];             // 65536 B
    const int t = threadIdx.x;
    const int row0 = blockIdx.x * 64;           // global row base (b*L + l)
    const int bidx = row0 >> 13;                // row / 8192 = batch index

    // stage A: 64 rows x 512 cols; each thread converts one 8-float chunk/iter
#pragma unroll
    for (int it = 0; it < 16; ++it) {
        int idx = t + it * 256;
        int r = idx >> 6, c = idx & 63;         // c = 8-element chunk id
        const float4* src = (const float4*)&sents[(size_t)(row0 + r) * 512 + (c << 3)];
        float4 f0 = src[0], f1 = src[1];
        v8bf v;
        v[0] = (__bf16)f0.x; v[1] = (__bf16)f0.y; v[2] = (__bf16)f0.z; v[3] = (__bf16)f0.w;
        v[4] = (__bf16)f1.x; v[5] = (__bf16)f1.y; v[6] = (__bf16)f1.z; v[7] = (__bf16)f1.w;
        *(v8bf*)&As[r * 512 + ((c ^ (r & 15)) << 3)] = v;
    }
    __syncthreads();

    const int wave = t >> 6, lane = t & 63;
    const int quad = lane >> 4, lcol = lane & 15;
    const int row_half = wave >> 1, col_half = wave & 1;
    const int rbase_local = row_half * 32;      // this wave's first row (a0 tile)

    float rowacc[8] = {0.f, 0.f, 0.f, 0.f, 0.f, 0.f, 0.f, 0.f};

    for (int ct = 0; ct < 8; ++ct) {
        const int c0 = (col_half * 8 + ct) * 32;
        const int ctg = c0 >> 4;
        v4f acc00 = {0.f, 0.f, 0.f, 0.f};
        v4f acc01 = {0.f, 0.f, 0.f, 0.f};
        v4f acc10 = {0.f, 0.f, 0.f, 0.f};
        v4f acc11 = {0.f, 0.f, 0.f, 0.f};
#pragma unroll
        for (int kt = 0; kt < 16; ++kt) {
            int sc = ((kt * 4 + quad) ^ lcol) << 3;     // swizzled chunk offset
            const __bf16* a0p = &As[(rbase_local + lcol) * 512 + sc];
            v8bf a0 = *(const v8bf*)a0p;
            v8bf a1 = *(const v8bf*)(a0p + 16 * 512);
            const __bf16* bp = &w2f[(size_t)((ctg * 16 + kt) * 64 + lane) * 8];
            v8bf b0 = *(const v8bf*)bp;
            v8bf b1 = *(const v8bf*)(bp + 16 * 64 * 8); // ctg+1 slab
            acc00 = __builtin_amdgcn_mfma_f32_16x16x32_bf16(a0, b0, acc00, 0, 0, 0);
            acc01 = __builtin_amdgcn_mfma_f32_16x16x32_bf16(a0, b1, acc01, 0, 0, 0);
            acc10 = __builtin_amdgcn_mfma_f32_16x16x32_bf16(a1, b0, acc10, 0, 0, 0);
            acc11 = __builtin_amdgcn_mfma_f32_16x16x32_bf16(a1, b1, acc11, 0, 0, 0);
        }
        // epilogue: tanh(eqc + v) * W3, accumulate per-row partials in regs
        float e0  = eqc[bidx * 512 + c0 + lcol];
        float e1  = eqc[bidx * 512 + c0 + 16 + lcol];
        float w30 = W3[c0 + lcol];
        float w31 = W3[c0 + 16 + lcol];
#pragma unroll
        for (int i = 0; i < 4; ++i) {
            rowacc[i]     += tanhf(e0 + acc00[i]) * w30 + tanhf(e1 + acc01[i]) * w31;
            rowacc[4 + i] += tanhf(e0 + acc10[i]) * w30 + tanhf(e1 + acc11[i]) * w31;
        }
    }
    // reduce over the 16 lanes of each quad (cols)
#pragma unroll
    for (int off = 1; off < 16; off <<= 1)
#pragma unroll
        for (int i = 0; i < 8; ++i) rowacc[i] += __shfl_xor(rowacc[i], off, 16);

    if (lcol == 0) {
        int rbase = row0 + rbase_local + quad * 4;
#pragma unroll
        for (int i = 0; i < 4; ++i) {
            atomicAdd(&logits[rbase + i], rowacc[i]);
            atomicAdd(&logits[rbase + 16 + i], rowacc[4 + i]);
        }
    }
}

// ---------------------------------------------------------------------------
// k3: per-batch softmax over L=8192 + inclusive cumsum -> sw (s), cw (c).
// ---------------------------------------------------------------------------
__global__ __launch_bounds__(256) void k3_softmax(const float* __restrict__ logits,
                                                  float* __restrict__ sw,
                                                  float* __restrict__ cw) {
    int b = blockIdx.x, t = threadIdx.x;
    const float* lg = logits + b * 8192;
    float v[32];
    float m = -1e30f;
#pragma unroll
    for (int i = 0; i < 32; ++i) { v[i] = lg[t * 32 + i]; m = fmaxf(m, v[i]); }
    __shared__ float red[256];
    red[t] = m; __syncthreads();
    for (int s = 128; s > 0; s >>= 1) {
        if (t < s) red[t] = fmaxf(red[t], red[t + s]);
        __syncthreads();
    }
    float M = red[0]; __syncthreads();
    float sum = 0.f;
#pragma unroll
    for (int i = 0; i < 32; ++i) { v[i] = expf(v[i] - M); sum += v[i]; }
    red[t] = sum; __syncthreads();
    // Hillis-Steele inclusive scan over per-thread sums
    for (int off = 1; off < 256; off <<= 1) {
        float add = (t >= off) ? red[t - off] : 0.f;
        __syncthreads();
        red[t] += add;
        __syncthreads();
    }
    float total = red[255];
    float excl = red[t] - sum;              // exclusive prefix of thread sums
    float inv = 1.f / total;
    float run = excl;
#pragma unroll
    for (int i = 0; i < 32; ++i) {
        run += v[i];
        sw[b * 8192 + t * 32 + i] = v[i] * inv;
        cw[b * 8192 + t * 32 + i] = run * inv;
    }
}

// ---------------------------------------------------------------------------
// k4: out = (c-s)*pre + s*self + (1-c)*pos   (fp32 streaming, float4/thread)
// ---------------------------------------------------------------------------
__global__ __launch_bounds__(256) void k4_combine(const float* __restrict__ sents,
                                                  const float* __restrict__ pre,
                                                  const float* __restrict__ pos,
                                                  const float* __restrict__ sw,
                                                  const float* __restrict__ cw,
                                                  float* __restrict__ out) {
    size_t g = (size_t)blockIdx.x * 256 + threadIdx.x;  // 8,388,608 threads
    size_t base = g << 2;                               // 4 floats per thread
    int row = (int)(g >> 7);                            // 128 threads per row
    float s = sw[row], c = cw[row];
    float pw = c - s, qw = 1.0f - c;
    float4 a = *(const float4*)&sents[base];
    float4 p = *(const float4*)&pre[base];
    float4 q = *(const float4*)&pos[base];
    float4 o;
    o.x = pw * p.x + s * a.x + qw * q.x;
    o.y = pw * p.y + s * a.y + qw * q.y;
    o.z = pw * p.z + s * a.z + qw * q.z;
    o.w = pw * p.w + s * a.w + qw * q.w;
    *(float4*)&out[base] = o;
}

// ---------------------------------------------------------------------------
extern "C" void kernel_launch(void* const* d_in, const int* in_sizes, int n_in,
                              void* d_out, int out_size, void* d_ws, size_t ws_size,
                              hipStream_t stream) {
    const float* emo   = (const float*)d_in[0];   // (8,1,512)
    const float* sents = (const float*)d_in[1];   // (8,8192,512)
    const float* pre   = (const float*)d_in[2];
    const float* pos   = (const float*)d_in[3];
    const float* W1    = (const float*)d_in[4];   // (512,512)
    const float* b1    = (const float*)d_in[5];
    const float* W2    = (const float*)d_in[6];   // (512,512)
    const float* b2    = (const float*)d_in[7];
    const float* W3    = (const float*)d_in[8];   // (512,1)
    // b3 = d_in[9]: constant shift -> cancels in softmax (and is zero)
    float* out = (float*)d_out;

    char* ws = (char*)d_ws;
    __bf16* w2f   = (__bf16*)ws;                    // 524288 B
    float* eqc    = (float*)(ws + 524288);          //  16384 B (8x512)
    float* logits = (float*)(ws + 540672);          // 262144 B (8x8192)
    float* sw     = (float*)(ws + 802816);          // 262144 B
    float* cw     = (float*)(ws + 1064960);         // 262144 B  (total ~1.27 MB)

    k0_w2swizzle<<<128, 256, 0, stream>>>(W2, w2f);
    k1_eq<<<8, 256, 0, stream>>>(emo, W1, b1, b2, eqc, logits);
    k2_logits<<<1024, 256, 0, stream>>>(sents, w2f, eqc, W3, logits);
    k3_softmax<<<8, 256, 0, stream>>>(logits, sw, cw);
    k4_combine<<<32768, 256, 0, stream>>>(sents, pre, pos, sw, cw, out);
}